// Round 5
// baseline (774.405 us; speedup 1.0000x reference)
//
#include <hip/hip_runtime.h>
#include <hip/hip_bf16.h>
#include <stdint.h>

// Round 5: counting-sort edges by weight_idx (64x reuse per weight), then the
// gathered 8x8 matvec runs with L1-resident weights (fp32, no conversion).
// Evidence: rounds 2-4 all sit at ~4 TB/s of L2-miss traffic (or equivalently
// MSHR-concurrency-bound); the only lever is fewer miss-lines per edge. Sort
// removes ~2 W miss-lines/edge (~270 MB) for ~100 MB of streaming sort cost.
//
// Pipeline (all in d_ws): zero bins -> histogram(widx) -> exclusive scan ->
// scatter {iidx,widx,eid} into sorted order -> main kernel over sorted stream,
// scattered 32B output stores. Output independent of atomic order (each edge
// independent) -> graph-replay safe.

#define NBINS 65536

// ---------- sort passes ----------

__global__ __launch_bounds__(256) void zero_bins_kernel(uint32_t* __restrict__ bins) {
    int i = blockIdx.x * blockDim.x + threadIdx.x;
    if (i < NBINS) bins[i] = 0u;
}

__global__ __launch_bounds__(256) void hist_kernel(
    const int* __restrict__ weight_idx, uint32_t* __restrict__ bins, int E) {
    int e = blockIdx.x * blockDim.x + threadIdx.x;
    if (e < E) atomicAdd(&bins[(uint32_t)weight_idx[e]], 1u);
}

// single-workgroup exclusive scan over 65536 bins (1024 thr x 64 elems)
__global__ __launch_bounds__(1024) void scan_kernel(uint32_t* __restrict__ bins) {
    __shared__ uint32_t sdata[1024];
    int t = threadIdx.x;
    uint32_t local[64];
    uint32_t sum = 0;
    int base_i = t * 64;
#pragma unroll
    for (int k = 0; k < 64; ++k) { local[k] = bins[base_i + k]; sum += local[k]; }
    sdata[t] = sum;
    __syncthreads();
    for (int off = 1; off < 1024; off <<= 1) {
        uint32_t v = (t >= off) ? sdata[t - off] : 0u;
        __syncthreads();
        sdata[t] += v;
        __syncthreads();
    }
    uint32_t run = sdata[t] - sum;   // exclusive prefix of this thread's range
#pragma unroll
    for (int k = 0; k < 64; ++k) { bins[base_i + k] = run; run += local[k]; }
}

__global__ __launch_bounds__(256) void scatter_kernel(
    const int* __restrict__ input_idx, const int* __restrict__ weight_idx,
    uint32_t* __restrict__ bins,
    uint32_t* __restrict__ s_iidx, uint32_t* __restrict__ s_widx,
    uint32_t* __restrict__ s_eid, int E) {
    int e = blockIdx.x * blockDim.x + threadIdx.x;
    if (e >= E) return;
    uint32_t w = (uint32_t)weight_idx[e];
    uint32_t i = (uint32_t)input_idx[e];
    uint32_t pos = atomicAdd(&bins[w], 1u);
    s_iidx[pos] = i;
    s_widx[pos] = w;
    s_eid[pos]  = (uint32_t)e;
}

// ---------- main: sorted stream, fp32 weights (L1-hit via widx runs) ----------

__global__ __launch_bounds__(256) void edge_linear_sorted_kernel(
    const float*    __restrict__ values,   // fp32[NUM_VALUES][8]
    const float*    __restrict__ weights,  // fp32[NUM_WEIGHTS][8][8]
    const uint32_t* __restrict__ s_iidx,
    const uint32_t* __restrict__ s_widx,
    const uint32_t* __restrict__ s_eid,
    float*          __restrict__ out,      // fp32[E][8]
    int E)
{
    int gid = blockIdx.x * blockDim.x + threadIdx.x;
    int j = gid >> 3;
    if (j >= E) return;
    int o = gid & 7;

    uint32_t iidx = s_iidx[j];
    uint32_t widx = s_widx[j];
    uint32_t eid  = s_eid[j];

    const float4* xp = (const float4*)(values  + (size_t)iidx * 8u);
    const float4* wp = (const float4*)(weights + (size_t)widx * 64u + (uint32_t)o * 8u);

    float4 x0 = xp[0], x1 = xp[1];
    float4 w0 = wp[0], w1 = wp[1];

    float acc = 0.0f;
    acc = fmaf(w0.x, x0.x, acc); acc = fmaf(w0.y, x0.y, acc);
    acc = fmaf(w0.z, x0.z, acc); acc = fmaf(w0.w, x0.w, acc);
    acc = fmaf(w1.x, x1.x, acc); acc = fmaf(w1.y, x1.y, acc);
    acc = fmaf(w1.z, x1.z, acc); acc = fmaf(w1.w, x1.w, acc);

    out[(size_t)eid * 8u + (uint32_t)o] = acc;
}

// ---------- fallbacks (round-4 path) ----------

__device__ __forceinline__ float bflo(uint32_t u) {
    union { uint32_t u; float f; } c; c.u = u << 16; return c.f;
}
__device__ __forceinline__ float bfhi(uint32_t u) {
    union { uint32_t u; float f; } c; c.u = u & 0xffff0000u; return c.f;
}

__global__ __launch_bounds__(256) void convert_weights_kernel(
    const float4* __restrict__ src, ushort4* __restrict__ dst, int n4) {
    int i = blockIdx.x * blockDim.x + threadIdx.x;
    if (i >= n4) return;
    float4 v = src[i];
    ushort4 r;
    r.x = __bfloat16_as_ushort(__float2bfloat16(v.x));
    r.y = __bfloat16_as_ushort(__float2bfloat16(v.y));
    r.z = __bfloat16_as_ushort(__float2bfloat16(v.z));
    r.w = __bfloat16_as_ushort(__float2bfloat16(v.w));
    dst[i] = r;
}

__global__ __launch_bounds__(256) void edge_linear_bf16w_kernel(
    const float* __restrict__ values, const uint32_t* __restrict__ wbf,
    const int* __restrict__ input_idx, const int* __restrict__ weight_idx,
    float* __restrict__ out, int E) {
    int gid = blockIdx.x * blockDim.x + threadIdx.x;
    int e = gid >> 3;
    if (e >= E) return;
    int o = gid & 7;
    int iidx = input_idx[e];
    int widx = weight_idx[e];
    const float4* xp = (const float4*)(values + (size_t)iidx * 8u);
    const uint4*  wp = (const uint4*)(wbf + (size_t)widx * 32u + (uint32_t)o * 4u);
    uint4 wv = *wp;
    float4 x0 = xp[0], x1 = xp[1];
    float acc = 0.0f;
    acc = fmaf(bflo(wv.x), x0.x, acc); acc = fmaf(bfhi(wv.x), x0.y, acc);
    acc = fmaf(bflo(wv.y), x0.z, acc); acc = fmaf(bfhi(wv.y), x0.w, acc);
    acc = fmaf(bflo(wv.z), x1.x, acc); acc = fmaf(bfhi(wv.z), x1.y, acc);
    acc = fmaf(bflo(wv.w), x1.z, acc); acc = fmaf(bfhi(wv.w), x1.w, acc);
    out[gid] = acc;
}

__global__ __launch_bounds__(256) void edge_linear_f32_kernel(
    const float* __restrict__ values, const float* __restrict__ weights,
    const int* __restrict__ input_idx, const int* __restrict__ weight_idx,
    float* __restrict__ out, int E) {
    int gid = blockIdx.x * blockDim.x + threadIdx.x;
    int e = gid >> 3;
    if (e >= E) return;
    int o = gid & 7;
    int iidx = input_idx[e];
    int widx = weight_idx[e];
    const float4* xp = (const float4*)(values  + (size_t)iidx * 8u);
    const float4* wp = (const float4*)(weights + (size_t)widx * 64u + (uint32_t)o * 8u);
    float4 x0 = xp[0], x1 = xp[1], w0 = wp[0], w1 = wp[1];
    float acc = 0.0f;
    acc = fmaf(w0.x, x0.x, acc); acc = fmaf(w0.y, x0.y, acc);
    acc = fmaf(w0.z, x0.z, acc); acc = fmaf(w0.w, x0.w, acc);
    acc = fmaf(w1.x, x1.x, acc); acc = fmaf(w1.y, x1.y, acc);
    acc = fmaf(w1.z, x1.z, acc); acc = fmaf(w1.w, x1.w, acc);
    out[gid] = acc;
}

// ---------- launch ----------

extern "C" void kernel_launch(void* const* d_in, const int* in_sizes, int n_in,
                              void* d_out, int out_size, void* d_ws, size_t ws_size,
                              hipStream_t stream) {
    const float* values     = (const float*)d_in[0];
    const float* weights    = (const float*)d_in[1];
    const int*   input_idx  = (const int*)d_in[2];
    const int*   weight_idx = (const int*)d_in[3];
    float*       out        = (float*)d_out;

    int E  = in_sizes[2];               // 4194304 edges
    int NW = in_sizes[1];               // weight-table element count (floats)

    size_t bins_bytes = (size_t)NBINS * 4u;
    size_t arr_bytes  = (size_t)E * 4u;
    size_t need_sort  = bins_bytes + 3u * arr_bytes;     // ~50.6 MB

    long long threads8 = (long long)E * 8;
    int block = 256;
    int grid8 = (int)((threads8 + block - 1) / block);
    int gridE = (E + block - 1) / block;

    if (ws_size >= need_sort) {
        uint32_t* bins   = (uint32_t*)d_ws;
        uint32_t* s_iidx = (uint32_t*)((char*)d_ws + bins_bytes);
        uint32_t* s_widx = (uint32_t*)((char*)d_ws + bins_bytes + arr_bytes);
        uint32_t* s_eid  = (uint32_t*)((char*)d_ws + bins_bytes + 2u * arr_bytes);

        zero_bins_kernel<<<NBINS / 256, 256, 0, stream>>>(bins);
        hist_kernel<<<gridE, 256, 0, stream>>>(weight_idx, bins, E);
        scan_kernel<<<1, 1024, 0, stream>>>(bins);
        scatter_kernel<<<gridE, 256, 0, stream>>>(input_idx, weight_idx, bins,
                                                  s_iidx, s_widx, s_eid, E);
        edge_linear_sorted_kernel<<<grid8, block, 0, stream>>>(
            values, weights, s_iidx, s_widx, s_eid, out, E);
    } else if (ws_size >= (size_t)NW * 2u) {
        int n4 = NW / 4;
        convert_weights_kernel<<<(n4 + 255) / 256, 256, 0, stream>>>(
            (const float4*)weights, (ushort4*)d_ws, n4);
        edge_linear_bf16w_kernel<<<grid8, block, 0, stream>>>(
            values, (const uint32_t*)d_ws, input_idx, weight_idx, out, E);
    } else {
        edge_linear_f32_kernel<<<grid8, block, 0, stream>>>(
            values, weights, input_idx, weight_idx, out, E);
    }
}